// Round 4
// baseline (71.460 us; speedup 1.0000x reference)
//
#include <hip/hip_runtime.h>

#define NN   640
#define NW   20    // 640/32 bitmask words per node
#define H    64
#define MAXD 80    // degree cap (mean deg ~24, Poisson tail: P(deg>80) ~ 0)

// Single fused kernel: block = node v, 512 threads = 8 waves.
// Phase A: build the FULL 640-node adjacency bitmask in LDS (51.2 KB) from the edge list.
// Phase B: enumerate N(v) + prefix-popcount position table.
// Phase C: compute xa[u] = x[u] @ W1a for u in N(v) into LDS (covers all S2 gathers).
// Phase D: per-pair hidden accumulation with ReLU (waves round-robin pairs).
// Phase E: linear tail (agg = hsum@W1b + deg*b1b) + MLP0 on wave 0.
__global__ __launch_bounds__(512) void rnp_all(
    const int* __restrict__ ei, int E,
    const float* __restrict__ x,
    const float* __restrict__ W1a, const float* __restrict__ b1a,
    const float* __restrict__ W1b, const float* __restrict__ b1b,
    const float* __restrict__ W0a, const float* __restrict__ b0a,
    const float* __restrict__ W0b, const float* __restrict__ b0b,
    float* __restrict__ out)
{
    __shared__ unsigned sbits[NN * NW];          // 51.2 KB full adjacency
    __shared__ float    xrows[MAXD][H];          // 20.5 KB xa rows for N(v)
    __shared__ float    hsum[H];
    __shared__ unsigned short ulist[MAXD];
    __shared__ int      pre[NW];
    __shared__ int      s_deg;

    const int v = blockIdx.x, t = threadIdx.x;
    const int lane = t & 63, wave = t >> 6;

    // ---- Phase A: zero + scatter edges into LDS bitmask ----
    for (int i = t; i < NN * NW; i += 512) sbits[i] = 0u;
    if (t < H) hsum[t] = 0.f;
    __syncthreads();
    for (int k = t; k < E; k += 512) {
        int a = ei[k], b = ei[k + E];
        if (a != b) atomicOr(&sbits[a * NW + (b >> 5)], 1u << (b & 31));
    }
    __syncthreads();

    const unsigned* rowv = &sbits[v * NW];

    // ---- Phase B: neighbor list + per-word prefix positions ----
    if (wave == 0 && lane < NW) {
        int off = 0;
        for (int i = 0; i < lane; ++i) off += __popc(rowv[i]);
        pre[lane] = off;
        unsigned c = rowv[lane];
        while (c) {
            int b = __ffs(c) - 1; c &= c - 1;
            if (off < MAXD) ulist[off] = (unsigned short)(lane * 32 + b);
            ++off;
        }
        if (lane == NW - 1) s_deg = (off < MAXD) ? off : MAXD;
    }
    __syncthreads();
    const int deg = s_deg;

    // ---- Phase C: xa rows for u in N(v) ----
    for (int p = wave; p < deg; p += 8) {
        const int u = ulist[p];
        const float xv = x[u * H + lane];
        float acc = 0.f;
        #pragma unroll
        for (int k = 0; k < H; ++k)
            acc += __shfl(xv, k, 64) * W1a[k * H + lane];
        xrows[p][lane] = acc;
    }
    __syncthreads();

    // ---- Phase D: per-pair hidden accumulation ----
    const float r64 = W1a[64 * H + lane];
    const float c0  = b1a[lane] + r64;            // b1a + 1*W1a[64]
    const float c1  = r64 + W1a[65 * H + lane];   // per-cnt term

    float hacc = 0.f;
    for (int p = wave; p < deg; p += 8) {
        const int u = ulist[p];
        const unsigned* bu = &sbits[u * NW];
        int cnt = 0; float xs = 0.f;
        #pragma unroll
        for (int j = 0; j < NW; ++j) {
            unsigned c = rowv[j] & bu[j];
            cnt += __popc(c);
            while (c) {
                int b = __ffs(c) - 1; c &= c - 1;
                int pos = pre[j] + __popc(rowv[j] & ((1u << b) - 1));
                xs += xrows[pos][lane];           // sum of xa over common nbrs
            }
        }
        float h = xrows[p][lane] + xs + c0 + (float)cnt * c1;
        hacc += fmaxf(h, 0.f);                    // ReLU then accumulate
    }
    atomicAdd(&hsum[lane], hacc);
    __syncthreads();

    // ---- Phase E: tail on wave 0: agg = hsum@W1b + deg*b1b; then MLP0 ----
    if (wave == 0) {
        const float fdeg = (float)deg;
        const float hs = hsum[lane];

        float a = fdeg * b1b[lane];
        #pragma unroll
        for (int d = 0; d < H; ++d) a += __shfl(hs, d, 64) * W1b[d * 65 + lane];

        float pp = hs * W1b[lane * 65 + 64];
        #pragma unroll
        for (int off = 32; off; off >>= 1) pp += __shfl_xor(pp, off, 64);
        const float agg64 = pp + fdeg * b1b[64];

        const float inp = x[v * H + lane] + a;    // hv + agg (first 64)
        float h = b0a[lane] + agg64 * W0a[64 * H + lane];
        #pragma unroll
        for (int k = 0; k < H; ++k) h += __shfl(inp, k, 64) * W0a[k * H + lane];
        h = fmaxf(h, 0.f);

        float o = b0b[lane];
        #pragma unroll
        for (int d = 0; d < H; ++d) o += __shfl(h, d, 64) * W0b[d * H + lane];
        out[v * H + lane] = o;
    }
}

extern "C" void kernel_launch(void* const* d_in, const int* in_sizes, int n_in,
                              void* d_out, int out_size, void* d_ws, size_t ws_size,
                              hipStream_t stream) {
    const float* x   = (const float*)d_in[0];
    const float* W1a = (const float*)d_in[1];
    const float* b1a = (const float*)d_in[2];
    const float* W1b = (const float*)d_in[3];
    const float* b1b = (const float*)d_in[4];
    const float* W0a = (const float*)d_in[5];
    const float* b0a = (const float*)d_in[6];
    const float* W0b = (const float*)d_in[7];
    const float* b0b = (const float*)d_in[8];
    const int*   ei  = (const int*)d_in[9];
    const int    E   = in_sizes[9] / 2;

    rnp_all<<<NN, 512, 0, stream>>>(ei, E, x, W1a, b1a, W1b, b1b,
                                    W0a, b0a, W0b, b0b, (float*)d_out);
}

// Round 5
// 33.313 us; speedup vs baseline: 2.1451x; 2.1451x over previous
//
#include <hip/hip_runtime.h>

#define NN   640
#define NW   20    // 640/32 bitmask words per node
#define H    64
#define MAXD 96    // degree cap; deg ~ Binomial(1279, .0187): mean 23.9, +15 sigma < 96

// ---------------- K1: prep ----------------
// blocks 0..159 : adjacency bitmask (4 nodes/block, LDS scatter) + xa = x@W1a, xc = x@W0a
// blocks 160..175: Wf = W1b @ W0a   (64x64, 4 rows/block)
// block  176     : bf = b1b @ W0a
__global__ __launch_bounds__(256) void prep(
    const int* __restrict__ ei, int E,
    const float* __restrict__ x,
    const float* __restrict__ W1a, const float* __restrict__ W0a,
    const float* __restrict__ W1b, const float* __restrict__ b1b,
    unsigned* __restrict__ bits, float* __restrict__ xa, float* __restrict__ xc,
    float* __restrict__ Wf, float* __restrict__ bf)
{
    const int t = threadIdx.x, lane = t & 63, wave = t >> 6, bid = blockIdx.x;

    if (bid < 160) {
        __shared__ unsigned sb[4 * NW];
        if (t < 4 * NW) sb[t] = 0u;
        __syncthreads();
        for (int k = t; k < E; k += 256) {
            int a = ei[k];
            if ((a >> 2) == bid) {
                int b = ei[k + E];
                if (b != a) atomicOr(&sb[(a & 3) * NW + (b >> 5)], 1u << (b & 31));
            }
        }
        __syncthreads();
        if (t < 4 * NW) bits[bid * 4 * NW + t] = sb[t];

        const int v = bid * 4 + wave;
        const float xv = x[v * H + lane];
        float a0 = 0, a1 = 0, a2 = 0, a3 = 0, c0 = 0, c1 = 0, c2 = 0, c3 = 0;
        #pragma unroll
        for (int k = 0; k < H; k += 4) {
            float s0 = __shfl(xv, k, 64),     s1 = __shfl(xv, k + 1, 64);
            float s2 = __shfl(xv, k + 2, 64), s3 = __shfl(xv, k + 3, 64);
            a0 += s0 * W1a[k * H + lane];       a1 += s1 * W1a[(k + 1) * H + lane];
            a2 += s2 * W1a[(k + 2) * H + lane]; a3 += s3 * W1a[(k + 3) * H + lane];
            c0 += s0 * W0a[k * H + lane];       c1 += s1 * W0a[(k + 1) * H + lane];
            c2 += s2 * W0a[(k + 2) * H + lane]; c3 += s3 * W0a[(k + 3) * H + lane];
        }
        xa[v * H + lane] = (a0 + a1) + (a2 + a3);
        xc[v * H + lane] = (c0 + c1) + (c2 + c3);
    } else if (bid < 176) {
        const int d = (bid - 160) * 4 + wave;
        const float wv = W1b[d * 65 + lane];          // lane e holds W1b[d][e]
        float a0 = 0, a1 = 0, a2 = 0, a3 = 0;
        #pragma unroll
        for (int e = 0; e < 64; e += 4) {
            a0 += __shfl(wv, e, 64)     * W0a[e * H + lane];
            a1 += __shfl(wv, e + 1, 64) * W0a[(e + 1) * H + lane];
            a2 += __shfl(wv, e + 2, 64) * W0a[(e + 2) * H + lane];
            a3 += __shfl(wv, e + 3, 64) * W0a[(e + 3) * H + lane];
        }
        Wf[d * H + lane] = (a0 + a1) + (a2 + a3) + W1b[d * 65 + 64] * W0a[64 * H + lane];
    } else if (wave == 0) {
        const float bv = b1b[lane];
        float a0 = 0, a1 = 0, a2 = 0, a3 = 0;
        #pragma unroll
        for (int e = 0; e < 64; e += 4) {
            a0 += __shfl(bv, e, 64)     * W0a[e * H + lane];
            a1 += __shfl(bv, e + 1, 64) * W0a[(e + 1) * H + lane];
            a2 += __shfl(bv, e + 2, 64) * W0a[(e + 2) * H + lane];
            a3 += __shfl(bv, e + 3, 64) * W0a[(e + 3) * H + lane];
        }
        bf[lane] = (a0 + a1) + (a2 + a3) + b1b[64] * W0a[64 * H + lane];
    }
}

// ---------------- K2: fused per-node ego computation ----------------
// block = node v; 8 waves. Stage neighbor bit-rows + xa rows into LDS, then an
// LDS-local pair loop, per-wave partials, and a 2-matvec tail on wave 0.
__global__ __launch_bounds__(512) void fused(
    const float* __restrict__ xa,  const float* __restrict__ xc,
    const float* __restrict__ W1a, const float* __restrict__ b1a,
    const float* __restrict__ Wf,  const float* __restrict__ bf,
    const float* __restrict__ b0a,
    const float* __restrict__ W0b, const float* __restrict__ b0b,
    const unsigned* __restrict__ bits,
    float* __restrict__ out)
{
    __shared__ __align__(16) unsigned rowv[NW];
    __shared__ __align__(16) unsigned nb[MAXD][NW];   // neighbor bit-rows
    __shared__ float xr[MAXD][H];                     // neighbor xa rows
    __shared__ float hpart[8][H];
    __shared__ float hshare[H];
    __shared__ unsigned short ulist[MAXD];
    __shared__ int pre[NW];
    __shared__ int s_deg;

    const int v = blockIdx.x, t = threadIdx.x;
    const int lane = t & 63, wave = t >> 6;

    if (t < NW) rowv[t] = bits[v * NW + t];
    __syncthreads();

    // enumeration: lane j owns bitmask word j; pre[j] = prefix popcount
    if (wave == 0 && lane < NW) {
        int off = 0;
        for (int i = 0; i < lane; ++i) off += __popc(rowv[i]);
        pre[lane] = off;
        unsigned c = rowv[lane];
        while (c) {
            int b = __ffs(c) - 1; c &= c - 1;
            if (off < MAXD) ulist[off] = (unsigned short)(lane * 32 + b);
            ++off;
        }
        if (lane == NW - 1) s_deg = (off < MAXD) ? off : MAXD;
    }
    __syncthreads();
    const int deg = s_deg;

    // stage neighbor bit-rows (3 rows per wave-iter, lanes 0..59) and xa rows
    {
        const int sub = lane / 20, word = lane - sub * 20;
        if (lane < 60)
            for (int p = wave * 3 + sub; p < deg; p += 24)
                nb[p][word] = bits[ulist[p] * NW + word];
    }
    for (int p = wave; p < deg; p += 8)
        xr[p][lane] = xa[ulist[p] * H + lane];
    __syncthreads();

    // register copies of v's row + constants
    unsigned rw[NW];
    #pragma unroll
    for (int j = 0; j < NW; ++j) rw[j] = rowv[j];
    const float r64 = W1a[64 * H + lane];
    const float k0  = b1a[lane] + r64;            // b1a + 1*W1a[64]
    const float k1  = r64 + W1a[65 * H + lane];   // per-cnt term

    float hacc = 0.f;
    for (int p = wave; p < deg; p += 8) {
        const uint4* bu = (const uint4*)nb[p];
        const uint4 q0 = bu[0], q1 = bu[1], q2 = bu[2], q3 = bu[3], q4 = bu[4];
        unsigned cw[NW] = {
            rw[0]  & q0.x, rw[1]  & q0.y, rw[2]  & q0.z, rw[3]  & q0.w,
            rw[4]  & q1.x, rw[5]  & q1.y, rw[6]  & q1.z, rw[7]  & q1.w,
            rw[8]  & q2.x, rw[9]  & q2.y, rw[10] & q2.z, rw[11] & q2.w,
            rw[12] & q3.x, rw[13] & q3.y, rw[14] & q3.z, rw[15] & q3.w,
            rw[16] & q4.x, rw[17] & q4.y, rw[18] & q4.z, rw[19] & q4.w };
        int cnt = 0;
        #pragma unroll
        for (int j = 0; j < NW; ++j) cnt += __popc(cw[j]);
        float xs = 0.f;
        #pragma unroll
        for (int j = 0; j < NW; ++j) {
            unsigned c = cw[j];
            while (c) {
                int b = __ffs(c) - 1; c &= c - 1;
                int pos = pre[j] + __popc(rw[j] & ((1u << b) - 1));
                xs += xr[pos][lane];              // xa of common neighbor (LDS)
            }
        }
        float h = xr[p][lane] + xs + k0 + (float)cnt * k1;
        hacc += fmaxf(h, 0.f);                    // ReLU then accumulate
    }
    hpart[wave][lane] = hacc;                     // deterministic partials
    __syncthreads();

    // ---- tail on wave 0: h = relu(xc_v + hsum@Wf + deg*bf + b0a); out = h@W0b + b0b
    if (wave == 0) {
        float hs = 0.f;
        #pragma unroll
        for (int w = 0; w < 8; ++w) hs += hpart[w][lane];
        hshare[lane] = hs;
        asm volatile("s_waitcnt lgkmcnt(0)" ::: "memory");

        float t0 = 0, t1 = 0, t2 = 0, t3 = 0;
        #pragma unroll
        for (int d = 0; d < H; d += 4) {
            t0 += hshare[d]     * Wf[d * H + lane];
            t1 += hshare[d + 1] * Wf[(d + 1) * H + lane];
            t2 += hshare[d + 2] * Wf[(d + 2) * H + lane];
            t3 += hshare[d + 3] * Wf[(d + 3) * H + lane];
        }
        const float fdeg = (float)deg;
        float hh = xc[v * H + lane] + fdeg * bf[lane] + b0a[lane] + (t0 + t1) + (t2 + t3);
        hh = fmaxf(hh, 0.f);
        hshare[lane] = hh;
        asm volatile("s_waitcnt lgkmcnt(0)" ::: "memory");

        float o0 = 0, o1 = 0, o2 = 0, o3 = 0;
        #pragma unroll
        for (int d = 0; d < H; d += 4) {
            o0 += hshare[d]     * W0b[d * H + lane];
            o1 += hshare[d + 1] * W0b[(d + 1) * H + lane];
            o2 += hshare[d + 2] * W0b[(d + 2) * H + lane];
            o3 += hshare[d + 3] * W0b[(d + 3) * H + lane];
        }
        out[v * H + lane] = b0b[lane] + (o0 + o1) + (o2 + o3);
    }
}

extern "C" void kernel_launch(void* const* d_in, const int* in_sizes, int n_in,
                              void* d_out, int out_size, void* d_ws, size_t ws_size,
                              hipStream_t stream) {
    const float* x   = (const float*)d_in[0];
    const float* W1a = (const float*)d_in[1];
    const float* b1a = (const float*)d_in[2];
    const float* W1b = (const float*)d_in[3];
    const float* b1b = (const float*)d_in[4];
    const float* W0a = (const float*)d_in[5];
    const float* b0a = (const float*)d_in[6];
    const float* W0b = (const float*)d_in[7];
    const float* b0b = (const float*)d_in[8];
    const int*   ei  = (const int*)d_in[9];
    const int    E   = in_sizes[9] / 2;

    char* ws = (char*)d_ws;
    unsigned* bits = (unsigned*)(ws);                       // 51200 B
    float*    xa   = (float*)(ws + 51200);                  // 163840 B
    float*    xc   = (float*)(ws + 51200 + 163840);         // 163840 B
    float*    Wf   = (float*)(ws + 51200 + 2 * 163840);     // 16384 B
    float*    bf   = (float*)(ws + 51200 + 2 * 163840 + 16384);

    prep<<<177, 256, 0, stream>>>(ei, E, x, W1a, W0a, W1b, b1b, bits, xa, xc, Wf, bf);
    fused<<<NN, 512, 0, stream>>>(xa, xc, W1a, b1a, Wf, bf, b0a, W0b, b0b,
                                  bits, (float*)d_out);
}

// Round 6
// 24.374 us; speedup vs baseline: 2.9318x; 1.3667x over previous
//
#include <hip/hip_runtime.h>

#define NN   640
#define NW   20    // used bitmask words per node
#define NWP  24    // padded row stride (96 B -> every row 16B-aligned)
#define H    64
#define MAXD 96    // degree cap; deg ~ Binomial(1279,.0187), mean 23.9

// ---------------- K1: prep ----------------
// blocks 0..319 : adjacency bitmask rows for 2 nodes (LDS scatter over edge list,
//                 30 iterations @ 512 threads) + xa = x@W1a, xc = x@W0a for those nodes
// blocks 320..327: Wf = W1b @ W0a (8 rows/block, one row per wave)
// block  328     : bf = b1b @ W0a
__global__ __launch_bounds__(512) void prep(
    const int* __restrict__ ei, int E,
    const float* __restrict__ x,
    const float* __restrict__ W1a, const float* __restrict__ W0a,
    const float* __restrict__ W1b, const float* __restrict__ b1b,
    unsigned* __restrict__ bits, float* __restrict__ xa, float* __restrict__ xc,
    float* __restrict__ Wf, float* __restrict__ bf)
{
    const int t = threadIdx.x, lane = t & 63, wave = t >> 6, bid = blockIdx.x;

    if (bid < 320) {
        __shared__ unsigned sb[2 * NW];
        if (t < 2 * NW) sb[t] = 0u;
        __syncthreads();
        for (int k = t; k < E; k += 512) {
            int a = ei[k];
            if ((a >> 1) == bid) {
                int b = ei[k + E];
                if (b != a) atomicOr(&sb[(a & 1) * NW + (b >> 5)], 1u << (b & 31));
            }
        }
        __syncthreads();
        if (t < 2 * NW) bits[(bid * 2 + t / NW) * NWP + (t % NW)] = sb[t];

        if (wave < 4) {                       // waves 0,1: xa; waves 2,3: xc
            const int v = bid * 2 + (wave & 1);
            const float* W = (wave < 2) ? W1a : W0a;
            const float xv = x[v * H + lane];
            float a0 = 0, a1 = 0, a2 = 0, a3 = 0;
            #pragma unroll
            for (int k = 0; k < H; k += 4) {
                a0 += __shfl(xv, k, 64)     * W[k * H + lane];
                a1 += __shfl(xv, k + 1, 64) * W[(k + 1) * H + lane];
                a2 += __shfl(xv, k + 2, 64) * W[(k + 2) * H + lane];
                a3 += __shfl(xv, k + 3, 64) * W[(k + 3) * H + lane];
            }
            float r = (a0 + a1) + (a2 + a3);
            if (wave < 2) xa[v * H + lane] = r; else xc[v * H + lane] = r;
        }
    } else if (bid < 328) {
        const int d = (bid - 320) * 8 + wave;
        const float wv = W1b[d * 65 + lane];          // lane e holds W1b[d][e]
        float a0 = 0, a1 = 0, a2 = 0, a3 = 0;
        #pragma unroll
        for (int e = 0; e < 64; e += 4) {
            a0 += __shfl(wv, e, 64)     * W0a[e * H + lane];
            a1 += __shfl(wv, e + 1, 64) * W0a[(e + 1) * H + lane];
            a2 += __shfl(wv, e + 2, 64) * W0a[(e + 2) * H + lane];
            a3 += __shfl(wv, e + 3, 64) * W0a[(e + 3) * H + lane];
        }
        Wf[d * H + lane] = (a0 + a1) + (a2 + a3) + W1b[d * 65 + 64] * W0a[64 * H + lane];
    } else if (wave == 0) {
        const float bv = b1b[lane];
        float a0 = 0, a1 = 0, a2 = 0, a3 = 0;
        #pragma unroll
        for (int e = 0; e < 64; e += 4) {
            a0 += __shfl(bv, e, 64)     * W0a[e * H + lane];
            a1 += __shfl(bv, e + 1, 64) * W0a[(e + 1) * H + lane];
            a2 += __shfl(bv, e + 2, 64) * W0a[(e + 2) * H + lane];
            a3 += __shfl(bv, e + 3, 64) * W0a[(e + 3) * H + lane];
        }
        bf[lane] = (a0 + a1) + (a2 + a3) + b1b[64] * W0a[64 * H + lane];
    }
}

// ---------------- K2: fused per-node ego computation ----------------
// block = node v; 8 waves. Round-3 direct-gather pair loop (best measured),
// deterministic per-wave partials, tail matvecs parallelized across waves.
__global__ __launch_bounds__(512) void fused(
    const float* __restrict__ xa,  const float* __restrict__ xc,
    const float* __restrict__ W1a, const float* __restrict__ b1a,
    const float* __restrict__ Wf,  const float* __restrict__ bf,
    const float* __restrict__ b0a,
    const float* __restrict__ W0b, const float* __restrict__ b0b,
    const unsigned* __restrict__ bits,
    float* __restrict__ out)
{
    __shared__ __align__(16) unsigned rowv[NW];
    __shared__ float hpart[8][H];
    __shared__ float hshare[H];
    __shared__ unsigned short ulist[MAXD];
    __shared__ int s_deg;

    const int v = blockIdx.x, t = threadIdx.x;
    const int lane = t & 63, wave = t >> 6;

    if (t < NW) rowv[t] = bits[v * NWP + t];
    __syncthreads();

    // neighbor enumeration: lane j owns bitmask word j
    if (wave == 0 && lane < NW) {
        int off = 0;
        for (int i = 0; i < lane; ++i) off += __popc(rowv[i]);
        unsigned c = rowv[lane];
        while (c) {
            int b = __ffs(c) - 1; c &= c - 1;
            if (off < MAXD) ulist[off] = (unsigned short)(lane * 32 + b);
            ++off;
        }
        if (lane == NW - 1) s_deg = (off < MAXD) ? off : MAXD;
    }
    __syncthreads();
    const int deg = s_deg;

    const float r64 = W1a[64 * H + lane];
    const float k0  = b1a[lane] + r64;            // b1a + 1*W1a[64]
    const float k1  = r64 + W1a[65 * H + lane];   // per-cnt term

    const uint4* rv4 = (const uint4*)rowv;
    const uint4 r0 = rv4[0], r1 = rv4[1], r2 = rv4[2], r3 = rv4[3], r4 = rv4[4];

    float hacc = 0.f;
    for (int p = wave; p < deg; p += 8) {
        const int u = ulist[p];
        const uint4* bu = (const uint4*)(bits + u * NWP);   // 16B-aligned (NWP=24)
        const uint4 q0 = bu[0], q1 = bu[1], q2 = bu[2], q3 = bu[3], q4 = bu[4];
        unsigned cw[NW] = {
            r0.x & q0.x, r0.y & q0.y, r0.z & q0.z, r0.w & q0.w,
            r1.x & q1.x, r1.y & q1.y, r1.z & q1.z, r1.w & q1.w,
            r2.x & q2.x, r2.y & q2.y, r2.z & q2.z, r2.w & q2.w,
            r3.x & q3.x, r3.y & q3.y, r3.z & q3.z, r3.w & q3.w,
            r4.x & q4.x, r4.y & q4.y, r4.z & q4.z, r4.w & q4.w };
        int cnt = 0;
        #pragma unroll
        for (int j = 0; j < NW; ++j) cnt += __popc(cw[j]);
        float xs = 0.f;
        #pragma unroll
        for (int j = 0; j < NW; ++j) {
            unsigned c = cw[j];
            while (c) {
                int b = __ffs(c) - 1; c &= c - 1;
                xs += xa[(j * 32 + b) * H + lane];   // xa of common neighbor
            }
        }
        float h = xa[u * H + lane] + xs + k0 + (float)cnt * k1;
        hacc += fmaxf(h, 0.f);                       // ReLU then accumulate
    }
    hpart[wave][lane] = hacc;                        // deterministic partials
    __syncthreads();

    // ---- tail, wave-parallel: h = relu(xc_v + hsum@Wf + deg*bf + b0a); out = h@W0b + b0b
    if (wave == 0) {
        float hs = 0.f;
        #pragma unroll
        for (int w = 0; w < 8; ++w) hs += hpart[w][lane];
        hshare[lane] = hs;
    }
    __syncthreads();
    {
        float s = 0.f;                               // wave w covers d in [8w, 8w+8)
        #pragma unroll
        for (int i = 0; i < 8; ++i) {
            const int d = wave * 8 + i;
            s += hshare[d] * Wf[d * H + lane];
        }
        hpart[wave][lane] = s;
    }
    __syncthreads();
    if (wave == 0) {
        float s = 0.f;
        #pragma unroll
        for (int w = 0; w < 8; ++w) s += hpart[w][lane];
        float hh = xc[v * H + lane] + (float)deg * bf[lane] + b0a[lane] + s;
        hshare[lane] = fmaxf(hh, 0.f);
    }
    __syncthreads();
    {
        float s = 0.f;
        #pragma unroll
        for (int i = 0; i < 8; ++i) {
            const int d = wave * 8 + i;
            s += hshare[d] * W0b[d * H + lane];
        }
        hpart[wave][lane] = s;
    }
    __syncthreads();
    if (wave == 0) {
        float s = 0.f;
        #pragma unroll
        for (int w = 0; w < 8; ++w) s += hpart[w][lane];
        out[v * H + lane] = b0b[lane] + s;
    }
}

extern "C" void kernel_launch(void* const* d_in, const int* in_sizes, int n_in,
                              void* d_out, int out_size, void* d_ws, size_t ws_size,
                              hipStream_t stream) {
    const float* x   = (const float*)d_in[0];
    const float* W1a = (const float*)d_in[1];
    const float* b1a = (const float*)d_in[2];
    const float* W1b = (const float*)d_in[3];
    const float* b1b = (const float*)d_in[4];
    const float* W0a = (const float*)d_in[5];
    const float* b0a = (const float*)d_in[6];
    const float* W0b = (const float*)d_in[7];
    const float* b0b = (const float*)d_in[8];
    const int*   ei  = (const int*)d_in[9];
    const int    E   = in_sizes[9] / 2;

    char* ws = (char*)d_ws;
    unsigned* bits = (unsigned*)(ws);                         // 640*24*4 = 61440 B
    float*    xa   = (float*)(ws + 61440);                    // 163840 B
    float*    xc   = (float*)(ws + 61440 + 163840);           // 163840 B
    float*    Wf   = (float*)(ws + 61440 + 2 * 163840);       // 16384 B
    float*    bf   = (float*)(ws + 61440 + 2 * 163840 + 16384);

    prep<<<329, 512, 0, stream>>>(ei, E, x, W1a, W0a, W1b, b1b, bits, xa, xc, Wf, bf);
    fused<<<NN, 512, 0, stream>>>(xa, xc, W1a, b1a, Wf, bf, b0a, W0b, b0b,
                                  bits, (float*)d_out);
}